// Round 1
// 13693.446 us; speedup vs baseline: 1.3460x; 1.3460x over previous
//
#include <hip/hip_runtime.h>
#include <stdint.h>
#include <stddef.h>

#define SEQ 1024
#define BATCH 64
#define HID 512   // H == D == 512

typedef short short8 __attribute__((ext_vector_type(8)));
typedef float floatx4 __attribute__((ext_vector_type(4)));

// ---- bf16 helpers (manual, RTN-even) ----
__device__ __forceinline__ unsigned short f2bf(float f) {
    unsigned u = __builtin_bit_cast(unsigned, f);
    u = (u + 0x7FFFu + ((u >> 16) & 1u)) >> 16;
    return (unsigned short)u;
}
__device__ __forceinline__ float bf2f(unsigned short b) {
    unsigned u = ((unsigned)b) << 16;
    return __builtin_bit_cast(float, u);
}

// ---- prep: split x (fp32 -> bf16 hi + bf16 lo), vectorized ----
__global__ void split_x_kernel(const float* __restrict__ x,
                               unsigned short* __restrict__ xh,
                               unsigned short* __restrict__ xl, int n4) {
    int idx = blockIdx.x * blockDim.x + threadIdx.x;
    int stride = gridDim.x * blockDim.x;
    const float4* x4 = (const float4*)x;
    for (int i = idx; i < n4; i += stride) {
        float4 v = x4[i];
        ushort4 h, l;
        h.x = f2bf(v.x); l.x = f2bf(v.x - bf2f(h.x));
        h.y = f2bf(v.y); l.y = f2bf(v.y - bf2f(h.y));
        h.z = f2bf(v.z); l.z = f2bf(v.z - bf2f(h.z));
        h.w = f2bf(v.w); l.w = f2bf(v.w - bf2f(h.w));
        *(ushort4*)(xh + 4 * (size_t)i) = h;
        *(ushort4*)(xl + 4 * (size_t)i) = l;
    }
}

// ---- prep: transpose + split the 4 weight matrices; also bias sums ----
__global__ void prep_w_kernel(const float* __restrict__ Wx0, const float* __restrict__ bx0,
                              const float* __restrict__ Wh0, const float* __restrict__ bh0,
                              const float* __restrict__ Wx1, const float* __restrict__ bx1,
                              const float* __restrict__ Wh1, const float* __restrict__ bh1,
                              unsigned short* __restrict__ Wth,
                              unsigned short* __restrict__ Wtl,
                              float* __restrict__ bsum) {
    int b = blockIdx.x;               // 0..2047
    int mat = b >> 9, k = b & 511;
    const float* Wsrc = (mat == 0) ? Wx0 : (mat == 1) ? Wh0 : (mat == 2) ? Wx1 : Wh1;
    for (int n = threadIdx.x; n < HID; n += blockDim.x) {
        float w = Wsrc[k * HID + n];
        unsigned short hi = f2bf(w);
        unsigned short lo = f2bf(w - bf2f(hi));
        size_t o = (size_t)mat * HID * HID + (size_t)n * HID + k;
        Wth[o] = hi;
        Wtl[o] = lo;
    }
    if (b == 0) for (int c = threadIdx.x; c < HID; c += blockDim.x) bsum[c] = bx0[c] + bh0[c];
    if (b == 1) for (int c = threadIdx.x; c < HID; c += blockDim.x) bsum[HID + c] = bx1[c] + bh1[c];
}

// ---- prep: init parity-1 h buffers from h0 input; zero barrier counters ----
__global__ void init_h_kernel(const float* __restrict__ h0in,
                              unsigned short* __restrict__ hh,
                              unsigned short* __restrict__ hl,
                              unsigned int* __restrict__ bar) {
    int i = blockIdx.x * blockDim.x + threadIdx.x;   // 0..65535
    if (blockIdx.x == 0 && threadIdx.x < 256) bar[threadIdx.x] = 0u;
    if (i >= 2 * BATCH * HID) return;
    int l = i >> 15, r = i & 32767;
    float v = h0in[i];
    unsigned short hi = f2bf(v), lo = f2bf(v - bf2f(hi));
    size_t o = (size_t)(l * 2 + 1) * (BATCH * HID) + r;
    hh[o] = hi;
    hl[o] = lo;
}

// ---- fallback per-step kernel (proven path, used only if cooperative launch fails) ----
__global__ __launch_bounds__(256) void rnn_step_kernel(
    int s,
    const unsigned short* __restrict__ xh, const unsigned short* __restrict__ xl,
    const unsigned short* __restrict__ Wth, const unsigned short* __restrict__ Wtl,
    const float* __restrict__ bsum,
    unsigned short* __restrict__ hh, unsigned short* __restrict__ hl,
    float* __restrict__ out) {
    const int HB = BATCH * HID;
    int wg = blockIdx.x;
    int layer = wg >> 5;
    int rg = (wg >> 3) & 3;
    int cg = wg & 7;
    int wave = threadIdx.x >> 6;
    int lane = threadIdx.x & 63;
    int lr = lane & 15, quad = lane >> 4;
    int col = cg * 64 + wave * 16 + lr;
    int row0 = rg * 16;

    const unsigned short *A1h, *A1l, *A2h, *A2l, *W1h, *W1l, *W2h, *W2l;
    int t;
    if (layer == 0) {
        if (s >= SEQ) return;
        t = s;
        A1h = xh + (size_t)(t * BATCH + row0) * HID;
        A1l = xl + (size_t)(t * BATCH + row0) * HID;
        int parR = (s + 1) & 1;
        A2h = hh + (size_t)(0 * 2 + parR) * HB + row0 * HID;
        A2l = hl + (size_t)(0 * 2 + parR) * HB + row0 * HID;
        W1h = Wth + 0 * (size_t)HID * HID; W1l = Wtl + 0 * (size_t)HID * HID;
        W2h = Wth + 1 * (size_t)HID * HID; W2l = Wtl + 1 * (size_t)HID * HID;
    } else {
        if (s < 1) return;
        t = s - 1;
        int parA = t & 1;
        A1h = hh + (size_t)(0 * 2 + parA) * HB + row0 * HID;
        A1l = hl + (size_t)(0 * 2 + parA) * HB + row0 * HID;
        int parB = (t + 1) & 1;
        A2h = hh + (size_t)(1 * 2 + parB) * HB + row0 * HID;
        A2l = hl + (size_t)(1 * 2 + parB) * HB + row0 * HID;
        W1h = Wth + 2 * (size_t)HID * HID; W1l = Wtl + 2 * (size_t)HID * HID;
        W2h = Wth + 3 * (size_t)HID * HID; W2l = Wtl + 3 * (size_t)HID * HID;
    }
    float bv = bsum[layer * HID + col];
    size_t aoff = (size_t)lr * HID + quad * 8;
    size_t woff = (size_t)col * HID + quad * 8;

    floatx4 accA = {0.f, 0.f, 0.f, 0.f};
    floatx4 accB = {0.f, 0.f, 0.f, 0.f};
#pragma unroll
    for (int kt = 0; kt < 16; ++kt) {
        int ko = kt * 32;
        short8 a1h = *(const short8*)(A1h + aoff + ko);
        short8 a1l = *(const short8*)(A1l + aoff + ko);
        short8 a2h = *(const short8*)(A2h + aoff + ko);
        short8 a2l = *(const short8*)(A2l + aoff + ko);
        short8 w1h = *(const short8*)(W1h + woff + ko);
        short8 w1l = *(const short8*)(W1l + woff + ko);
        short8 w2h = *(const short8*)(W2h + woff + ko);
        short8 w2l = *(const short8*)(W2l + woff + ko);
        accA = __builtin_amdgcn_mfma_f32_16x16x32_bf16(a1h, w1h, accA, 0, 0, 0);
        accB = __builtin_amdgcn_mfma_f32_16x16x32_bf16(a1l, w1h, accB, 0, 0, 0);
        accA = __builtin_amdgcn_mfma_f32_16x16x32_bf16(a1h, w1l, accA, 0, 0, 0);
        accB = __builtin_amdgcn_mfma_f32_16x16x32_bf16(a2h, w2h, accB, 0, 0, 0);
        accA = __builtin_amdgcn_mfma_f32_16x16x32_bf16(a2l, w2h, accA, 0, 0, 0);
        accB = __builtin_amdgcn_mfma_f32_16x16x32_bf16(a2h, w2l, accB, 0, 0, 0);
    }

    int parOut = t & 1;
    unsigned short* hhout = hh + (size_t)(layer * 2 + parOut) * HB;
    unsigned short* hlout = hl + (size_t)(layer * 2 + parOut) * HB;
#pragma unroll
    for (int i = 0; i < 4; ++i) {
        int row = row0 + quad * 4 + i;
        float p = accA[i] + accB[i] + bv;
        float e = __expf(2.0f * p);
        float th = 1.0f - 2.0f / (e + 1.0f);
        unsigned short thi = f2bf(th);
        unsigned short tlo = f2bf(th - bf2f(thi));
        hhout[(size_t)row * HID + col] = thi;
        hlout[(size_t)row * HID + col] = tlo;
        if (layer == 1) {
            out[((size_t)t * BATCH + row) * HID + col] = th;
            if (t == SEQ - 1)
                out[(size_t)SEQ * BATCH * HID + (size_t)(1 * BATCH + row) * HID + col] = th;
        } else if (t == SEQ - 1) {
            out[(size_t)SEQ * BATCH * HID + (size_t)(0 * BATCH + row) * HID + col] = th;
        }
    }
}

// ---- persistent cooperative kernel ----
// 256 blocks x 64 threads (1 wave/block, 1 block/CU). bid&7 ~ XCD (round-robin
// dispatch assumption; perf heuristic only). Group g = (bid&7)>>1 owns batch
// rows [16g,16g+16) -- an INDEPENDENT recurrent chain -> per-group barrier of
// 64 blocks. Within a group: layer(2) x colgroup(32 x 16 cols).
// Weights (16 cols x K=512 x 2 mats x hi/lo = 64KB) live in LDS for the whole
// sequence; col stride padded to 1040B -> bank-balanced ds_read_b128 with pure
// immediate-offset addressing.
#define COLSTRIDE 1040
__global__ __launch_bounds__(64, 1) void rnn_persist_kernel(
    const unsigned short* __restrict__ xh, const unsigned short* __restrict__ xl,
    const unsigned short* __restrict__ Wth, const unsigned short* __restrict__ Wtl,
    const float* __restrict__ bsum,
    unsigned short* __restrict__ hh, unsigned short* __restrict__ hl,
    float* __restrict__ out, unsigned int* __restrict__ bar) {
    extern __shared__ char lds_raw[];
    const int HB = BATCH * HID;
    int bid = blockIdx.x;
    int g = (bid & 7) >> 1;                       // row-group / chain id
    int idx = ((bid >> 3) << 1) | (bid & 1);      // 0..63 within group
    int layer = idx >> 5;
    int cg = idx & 31;
    int lane = threadIdx.x;                       // 0..63 (one wave)
    int lr = lane & 15, quad = lane >> 4;
    int row0 = g * 16;
    int col0 = cg * 16;
    int col = col0 + lr;
    int matbase = layer * 2;

    // ---- stage weight slice into LDS (once) ----
    // mh: 0=W1hi 1=W1lo 2=W2hi 3=W2lo ; c: col within slab ; slot: 16B chunk (k=slot*8)
    for (int i = lane; i < 4096; i += 64) {
        int mh = i >> 10, c = (i >> 6) & 15, slot = i & 63;
        const unsigned short* src = ((mh & 1) ? Wtl : Wth)
            + ((size_t)(matbase + (mh >> 1)) * HID + (col0 + c)) * HID + slot * 8;
        *(short8*)(lds_raw + (size_t)(mh * 16 + c) * COLSTRIDE + slot * 16) =
            *(const short8*)src;
    }
    // single wave: ds_write->ds_read ordering handled by compiler waitcnt

    float bv = bsum[layer * HID + col];
    unsigned int* cnt = bar + (g << 6);           // 256B-separated counters
    size_t aoff = (size_t)lr * HID + quad * 8;
    const char* wb0 = lds_raw + (size_t)(0 * 16 + lr) * COLSTRIDE + quad * 16;
    const char* wb1 = lds_raw + (size_t)(1 * 16 + lr) * COLSTRIDE + quad * 16;
    const char* wb2 = lds_raw + (size_t)(2 * 16 + lr) * COLSTRIDE + quad * 16;
    const char* wb3 = lds_raw + (size_t)(3 * 16 + lr) * COLSTRIDE + quad * 16;

    for (int s = 0; s <= SEQ; ++s) {
        bool active = (layer == 0) ? (s < SEQ) : (s >= 1);
        if (active) {
            int t = (layer == 0) ? s : (s - 1);
            const unsigned short *A1h, *A1l, *A2h, *A2l;
            if (layer == 0) {
                A1h = xh + ((size_t)t * BATCH + row0) * HID;
                A1l = xl + ((size_t)t * BATCH + row0) * HID;
                int parR = (s + 1) & 1;
                A2h = hh + (size_t)parR * HB + (size_t)row0 * HID;
                A2l = hl + (size_t)parR * HB + (size_t)row0 * HID;
            } else {
                int parA = t & 1;
                A1h = hh + (size_t)parA * HB + (size_t)row0 * HID;
                A1l = hl + (size_t)parA * HB + (size_t)row0 * HID;
                int parB = (t + 1) & 1;
                A2h = hh + (size_t)(2 + parB) * HB + (size_t)row0 * HID;
                A2l = hl + (size_t)(2 + parB) * HB + (size_t)row0 * HID;
            }
            floatx4 aA0 = {0.f, 0.f, 0.f, 0.f};
            floatx4 aB0 = {0.f, 0.f, 0.f, 0.f};
            floatx4 aA1 = {0.f, 0.f, 0.f, 0.f};
            floatx4 aB1 = {0.f, 0.f, 0.f, 0.f};
#define KSTEP(KT, AA, AB) do { \
    const int ko = (KT) * 32; \
    short8 a1h = *(const short8*)(A1h + aoff + ko); \
    short8 a1l = *(const short8*)(A1l + aoff + ko); \
    short8 a2h = *(const short8*)(A2h + aoff + ko); \
    short8 a2l = *(const short8*)(A2l + aoff + ko); \
    short8 w1h = *(const short8*)(wb0 + (KT) * 64); \
    short8 w1l = *(const short8*)(wb1 + (KT) * 64); \
    short8 w2h = *(const short8*)(wb2 + (KT) * 64); \
    short8 w2l = *(const short8*)(wb3 + (KT) * 64); \
    AA = __builtin_amdgcn_mfma_f32_16x16x32_bf16(a1h, w1h, AA, 0, 0, 0); \
    AB = __builtin_amdgcn_mfma_f32_16x16x32_bf16(a1l, w1h, AB, 0, 0, 0); \
    AA = __builtin_amdgcn_mfma_f32_16x16x32_bf16(a1h, w1l, AA, 0, 0, 0); \
    AB = __builtin_amdgcn_mfma_f32_16x16x32_bf16(a2h, w2h, AB, 0, 0, 0); \
    AA = __builtin_amdgcn_mfma_f32_16x16x32_bf16(a2l, w2h, AA, 0, 0, 0); \
    AB = __builtin_amdgcn_mfma_f32_16x16x32_bf16(a2h, w2l, AB, 0, 0, 0); \
} while (0)
#pragma unroll
            for (int kt = 0; kt < 16; kt += 2) {
                KSTEP(kt, aA0, aB0);
                KSTEP(kt + 1, aA1, aB1);
            }
#undef KSTEP
            int parOut = t & 1;
            unsigned short* hhout = hh + (size_t)(layer * 2 + parOut) * HB;
            unsigned short* hlout = hl + (size_t)(layer * 2 + parOut) * HB;
#pragma unroll
            for (int i = 0; i < 4; ++i) {
                int row = row0 + quad * 4 + i;
                float p = (aA0[i] + aB0[i]) + (aA1[i] + aB1[i]) + bv;
                float e = __expf(2.0f * p);
                float th = 1.0f - 2.0f / (e + 1.0f);
                unsigned short thi = f2bf(th);
                unsigned short tlo = f2bf(th - bf2f(thi));
                hhout[(size_t)row * HID + col] = thi;
                hlout[(size_t)row * HID + col] = tlo;
                if (layer == 1) {
                    out[((size_t)t * BATCH + row) * HID + col] = th;
                    if (t == SEQ - 1)
                        out[(size_t)SEQ * BATCH * HID + (size_t)(BATCH + row) * HID + col] = th;
                } else if (t == SEQ - 1) {
                    out[(size_t)SEQ * BATCH * HID + (size_t)row * HID + col] = th;
                }
            }
        }
        if (s < SEQ) {
            // ---- group barrier (monotonic counter, 64 blocks) ----
            __builtin_amdgcn_fence(__ATOMIC_RELEASE, "agent");   // wb L2
            if (lane == 0) {
                __hip_atomic_fetch_add(cnt, 1u, __ATOMIC_RELAXED, __HIP_MEMORY_SCOPE_AGENT);
                unsigned target = 64u * (unsigned)(s + 1);
                while (__hip_atomic_load(cnt, __ATOMIC_RELAXED, __HIP_MEMORY_SCOPE_AGENT) < target)
                    __builtin_amdgcn_s_sleep(1);
            }
            __builtin_amdgcn_fence(__ATOMIC_ACQUIRE, "agent");   // inv L2
        }
    }
}

extern "C" void kernel_launch(void* const* d_in, const int* in_sizes, int n_in,
                              void* d_out, int out_size, void* d_ws, size_t ws_size,
                              hipStream_t stream) {
    const float* x    = (const float*)d_in[0];
    const float* h0in = (const float*)d_in[1];
    const float* Wx0  = (const float*)d_in[2];
    const float* bx0  = (const float*)d_in[3];
    const float* Wh0  = (const float*)d_in[4];
    const float* bh0  = (const float*)d_in[5];
    const float* Wx1  = (const float*)d_in[6];
    const float* bx1  = (const float*)d_in[7];
    const float* Wh1  = (const float*)d_in[8];
    const float* bh1  = (const float*)d_in[9];
    float* out = (float*)d_out;

    // workspace layout (all 256B aligned)
    char* w = (char*)d_ws;
    const size_t XN = (size_t)SEQ * BATCH * HID;          // 33,554,432
    unsigned short* xh  = (unsigned short*)(w);                       // 64 MB
    unsigned short* xl  = (unsigned short*)(w + 2 * XN);              // 64 MB
    unsigned short* Wth = (unsigned short*)(w + 4 * XN);              // 2 MB
    unsigned short* Wtl = (unsigned short*)(w + 4 * XN + 2097152);    // 2 MB
    float*          bsum= (float*)        (w + 4 * XN + 4194304);     // 4 KB
    unsigned short* hh  = (unsigned short*)(w + 4 * XN + 4198400);    // 256 KB
    unsigned short* hl  = (unsigned short*)(w + 4 * XN + 4460544);    // 256 KB
    unsigned int*   bar = (unsigned int*) (w + 4 * XN + 4722688);     // 1 KB
    // total ~132.5 MB

    split_x_kernel<<<4096, 256, 0, stream>>>(x, xh, xl, (int)(XN / 4));
    prep_w_kernel<<<2048, 256, 0, stream>>>(Wx0, bx0, Wh0, bh0, Wx1, bx1, Wh1, bh1,
                                            Wth, Wtl, bsum);
    init_h_kernel<<<256, 256, 0, stream>>>(h0in, hh, hl, bar);

    // persistent cooperative kernel: whole scan in one launch
    void* args[9] = {(void*)&xh, (void*)&xl, (void*)&Wth, (void*)&Wtl, (void*)&bsum,
                     (void*)&hh, (void*)&hl, (void*)&out, (void*)&bar};
    hipError_t err = hipLaunchCooperativeKernel((const void*)rnn_persist_kernel,
                                                dim3(256), dim3(64), args,
                                                (unsigned)(4 * 16 * COLSTRIDE), stream);
    if (err != hipSuccess) {
        // fallback: proven per-step path (no perf regression below baseline)
        for (int s = 0; s <= SEQ; ++s) {
            rnn_step_kernel<<<64, 256, 0, stream>>>(s, xh, xl, Wth, Wtl, bsum, hh, hl, out);
        }
    }
}

// Round 4
// 7885.653 us; speedup vs baseline: 2.3373x; 1.7365x over previous
//
#include <hip/hip_runtime.h>
#include <stdint.h>
#include <stddef.h>

#define SEQ 1024
#define BATCH 64
#define HID 512   // H == D == 512
#define HBSZ (BATCH * HID)

typedef short short8 __attribute__((ext_vector_type(8)));
typedef float floatx4 __attribute__((ext_vector_type(4)));

// ---- bf16 helpers (manual, RTN-even) ----
__device__ __forceinline__ unsigned short f2bf(float f) {
    unsigned u = __builtin_bit_cast(unsigned, f);
    u = (u + 0x7FFFu + ((u >> 16) & 1u)) >> 16;
    return (unsigned short)u;
}
__device__ __forceinline__ float bf2f(unsigned short b) {
    unsigned u = ((unsigned)b) << 16;
    return __builtin_bit_cast(float, u);
}

// ---- prep: split x (fp32 -> bf16 hi + bf16 lo), vectorized ----
__global__ void split_x_kernel(const float* __restrict__ x,
                               unsigned short* __restrict__ xh,
                               unsigned short* __restrict__ xl, int n4) {
    int idx = blockIdx.x * blockDim.x + threadIdx.x;
    int stride = gridDim.x * blockDim.x;
    const float4* x4 = (const float4*)x;
    for (int i = idx; i < n4; i += stride) {
        float4 v = x4[i];
        ushort4 h, l;
        h.x = f2bf(v.x); l.x = f2bf(v.x - bf2f(h.x));
        h.y = f2bf(v.y); l.y = f2bf(v.y - bf2f(h.y));
        h.z = f2bf(v.z); l.z = f2bf(v.z - bf2f(h.z));
        h.w = f2bf(v.w); l.w = f2bf(v.w - bf2f(h.w));
        *(ushort4*)(xh + 4 * (size_t)i) = h;
        *(ushort4*)(xl + 4 * (size_t)i) = l;
    }
}

// ---- prep: transpose + split the 4 weight matrices; also bias sums ----
__global__ void prep_w_kernel(const float* __restrict__ Wx0, const float* __restrict__ bx0,
                              const float* __restrict__ Wh0, const float* __restrict__ bh0,
                              const float* __restrict__ Wx1, const float* __restrict__ bx1,
                              const float* __restrict__ Wh1, const float* __restrict__ bh1,
                              unsigned short* __restrict__ Wth,
                              unsigned short* __restrict__ Wtl,
                              float* __restrict__ bsum) {
    int b = blockIdx.x;               // 0..2047
    int mat = b >> 9, k = b & 511;
    const float* Wsrc = (mat == 0) ? Wx0 : (mat == 1) ? Wh0 : (mat == 2) ? Wx1 : Wh1;
    for (int n = threadIdx.x; n < HID; n += blockDim.x) {
        float w = Wsrc[k * HID + n];
        unsigned short hi = f2bf(w);
        unsigned short lo = f2bf(w - bf2f(hi));
        size_t o = (size_t)mat * HID * HID + (size_t)n * HID + k;
        Wth[o] = hi;
        Wtl[o] = lo;
    }
    if (b == 0) for (int c = threadIdx.x; c < HID; c += blockDim.x) bsum[c] = bx0[c] + bh0[c];
    if (b == 1) for (int c = threadIdx.x; c < HID; c += blockDim.x) bsum[HID + c] = bx1[c] + bh1[c];
}

// ---- prep: init parity-1 h buffers from h0 input; zero barrier counters ----
__global__ void init_h_kernel(const float* __restrict__ h0in,
                              unsigned short* __restrict__ hh,
                              unsigned short* __restrict__ hl,
                              unsigned int* __restrict__ bar) {
    int i = blockIdx.x * blockDim.x + threadIdx.x;   // 0..65535
    if (blockIdx.x == 0 && threadIdx.x < 256) bar[threadIdx.x] = 0u;
    if (i >= 2 * BATCH * HID) return;
    int l = i >> 15, r = i & 32767;
    float v = h0in[i];
    unsigned short hi = f2bf(v), lo = f2bf(v - bf2f(hi));
    size_t o = (size_t)(l * 2 + 1) * (BATCH * HID) + r;
    hh[o] = hi;
    hl[o] = lo;
}

// ---- fallback per-step kernel (proven path, used only if cooperative launch fails) ----
__global__ __launch_bounds__(256) void rnn_step_kernel(
    int s,
    const unsigned short* __restrict__ xh, const unsigned short* __restrict__ xl,
    const unsigned short* __restrict__ Wth, const unsigned short* __restrict__ Wtl,
    const float* __restrict__ bsum,
    unsigned short* __restrict__ hh, unsigned short* __restrict__ hl,
    float* __restrict__ out) {
    const int HB = BATCH * HID;
    int wg = blockIdx.x;
    int layer = wg >> 5;
    int rg = (wg >> 3) & 3;
    int cg = wg & 7;
    int wave = threadIdx.x >> 6;
    int lane = threadIdx.x & 63;
    int lr = lane & 15, quad = lane >> 4;
    int col = cg * 64 + wave * 16 + lr;
    int row0 = rg * 16;

    const unsigned short *A1h, *A1l, *A2h, *A2l, *W1h, *W1l, *W2h, *W2l;
    int t;
    if (layer == 0) {
        if (s >= SEQ) return;
        t = s;
        A1h = xh + (size_t)(t * BATCH + row0) * HID;
        A1l = xl + (size_t)(t * BATCH + row0) * HID;
        int parR = (s + 1) & 1;
        A2h = hh + (size_t)(0 * 2 + parR) * HB + row0 * HID;
        A2l = hl + (size_t)(0 * 2 + parR) * HB + row0 * HID;
        W1h = Wth + 0 * (size_t)HID * HID; W1l = Wtl + 0 * (size_t)HID * HID;
        W2h = Wth + 1 * (size_t)HID * HID; W2l = Wtl + 1 * (size_t)HID * HID;
    } else {
        if (s < 1) return;
        t = s - 1;
        int parA = t & 1;
        A1h = hh + (size_t)(0 * 2 + parA) * HB + row0 * HID;
        A1l = hl + (size_t)(0 * 2 + parA) * HB + row0 * HID;
        int parB = (t + 1) & 1;
        A2h = hh + (size_t)(1 * 2 + parB) * HB + row0 * HID;
        A2l = hl + (size_t)(1 * 2 + parB) * HB + row0 * HID;
        W1h = Wth + 2 * (size_t)HID * HID; W1l = Wtl + 2 * (size_t)HID * HID;
        W2h = Wth + 3 * (size_t)HID * HID; W2l = Wtl + 3 * (size_t)HID * HID;
    }
    float bv = bsum[layer * HID + col];
    size_t aoff = (size_t)lr * HID + quad * 8;
    size_t woff = (size_t)col * HID + quad * 8;

    floatx4 accA = {0.f, 0.f, 0.f, 0.f};
    floatx4 accB = {0.f, 0.f, 0.f, 0.f};
#pragma unroll
    for (int kt = 0; kt < 16; ++kt) {
        int ko = kt * 32;
        short8 a1h = *(const short8*)(A1h + aoff + ko);
        short8 a1l = *(const short8*)(A1l + aoff + ko);
        short8 a2h = *(const short8*)(A2h + aoff + ko);
        short8 a2l = *(const short8*)(A2l + aoff + ko);
        short8 w1h = *(const short8*)(W1h + woff + ko);
        short8 w1l = *(const short8*)(W1l + woff + ko);
        short8 w2h = *(const short8*)(W2h + woff + ko);
        short8 w2l = *(const short8*)(W2l + woff + ko);
        accA = __builtin_amdgcn_mfma_f32_16x16x32_bf16(a1h, w1h, accA, 0, 0, 0);
        accB = __builtin_amdgcn_mfma_f32_16x16x32_bf16(a1l, w1h, accB, 0, 0, 0);
        accA = __builtin_amdgcn_mfma_f32_16x16x32_bf16(a1h, w1l, accA, 0, 0, 0);
        accB = __builtin_amdgcn_mfma_f32_16x16x32_bf16(a2h, w2h, accB, 0, 0, 0);
        accA = __builtin_amdgcn_mfma_f32_16x16x32_bf16(a2l, w2h, accA, 0, 0, 0);
        accB = __builtin_amdgcn_mfma_f32_16x16x32_bf16(a2h, w2l, accB, 0, 0, 0);
    }

    int parOut = t & 1;
    unsigned short* hhout = hh + (size_t)(layer * 2 + parOut) * HB;
    unsigned short* hlout = hl + (size_t)(layer * 2 + parOut) * HB;
#pragma unroll
    for (int i = 0; i < 4; ++i) {
        int row = row0 + quad * 4 + i;
        float p = accA[i] + accB[i] + bv;
        float e = __expf(2.0f * p);
        float th = 1.0f - 2.0f / (e + 1.0f);
        unsigned short thi = f2bf(th);
        unsigned short tlo = f2bf(th - bf2f(thi));
        hhout[(size_t)row * HID + col] = thi;
        hlout[(size_t)row * HID + col] = tlo;
        if (layer == 1) {
            out[((size_t)t * BATCH + row) * HID + col] = th;
            if (t == SEQ - 1)
                out[(size_t)SEQ * BATCH * HID + (size_t)(1 * BATCH + row) * HID + col] = th;
        } else if (t == SEQ - 1) {
            out[(size_t)SEQ * BATCH * HID + (size_t)(0 * BATCH + row) * HID + col] = th;
        }
    }
}

// =====================================================================
// Persistent cooperative kernel, fence-free.
// h exchange: loads = compiler-generated agent-scope relaxed atomics (sc1,
// read the IF$ coherence point; compiler tracks all vmcnt hazards).
// stores = inline-asm global_store_short sc1 (operands read at issue: no
// async-writeback hazard). x loads plain (immutable). Weights in LDS.
// Barrier: s_waitcnt vmcnt(0) (release: sc1 stores acked at coherence
// point) -> relaxed agent fetch_add -> relaxed spin + s_sleep. No
// buffer_wbl2 / buffer_inv anywhere in the loop.
// =====================================================================
#define COLSTRIDE 1040

#define GST_H(val, voff, base, OFF) \
    asm volatile("global_store_short %0, %1, %2 offset:" #OFF " sc1" \
                 :: "v"(voff), "v"(val), "s"(base))

__device__ __forceinline__ short8 ald16(const unsigned short* p) {
    union { unsigned long long q[2]; short8 v; } u;
    u.q[0] = __hip_atomic_load((unsigned long long*)p,
                               __ATOMIC_RELAXED, __HIP_MEMORY_SCOPE_AGENT);
    u.q[1] = __hip_atomic_load((unsigned long long*)(p + 4),
                               __ATOMIC_RELAXED, __HIP_MEMORY_SCOPE_AGENT);
    return u.v;
}
__device__ __forceinline__ short8 pld16(const unsigned short* p) {
    return *(const short8*)p;
}

__global__ __launch_bounds__(64, 1) void rnn_persist_kernel(
    const unsigned short* __restrict__ xh, const unsigned short* __restrict__ xl,
    const unsigned short* __restrict__ Wth, const unsigned short* __restrict__ Wtl,
    const float* __restrict__ bsum,
    unsigned short* __restrict__ hh, unsigned short* __restrict__ hl,
    float* __restrict__ out, unsigned int* __restrict__ bar) {
    extern __shared__ char lds_raw[];
    int bid = blockIdx.x;
    int g = (bid & 7) >> 1;                       // row-group / chain id
    int idx = ((bid >> 3) << 1) | (bid & 1);      // 0..63 within group
    int layer = idx >> 5;
    int cg = idx & 31;
    int lane = threadIdx.x;                       // 0..63 (one wave)
    int lr = lane & 15, quad = lane >> 4;
    int row0 = g * 16;
    int col0 = cg * 16;
    int col = col0 + lr;
    int matbase = layer * 2;

    // ---- stage weight slice into LDS (once) ----
    // mh: 0=W1hi 1=W1lo 2=W2hi 3=W2lo ; c: col within slab ; slot: 16B chunk
    for (int i = lane; i < 4096; i += 64) {
        int mh = i >> 10, c = (i >> 6) & 15, slot = i & 63;
        const unsigned short* src = ((mh & 1) ? Wtl : Wth)
            + ((size_t)(matbase + (mh >> 1)) * HID + (col0 + c)) * HID + slot * 8;
        *(short8*)(lds_raw + (size_t)(mh * 16 + c) * COLSTRIDE + slot * 16) =
            *(const short8*)src;
    }

    float bv = bsum[layer * HID + col];
    unsigned int* cnt = bar + (g << 6);           // 256B-separated counters
    size_t aoff = (size_t)lr * HID + quad * 8;    // elements
    unsigned hvoff = (unsigned)((((row0 + quad * 4) * HID) + col) * 2);  // bytes
    const char* wb0 = lds_raw + (size_t)(0 * 16 + lr) * COLSTRIDE + quad * 16;
    const char* wb1 = lds_raw + (size_t)(1 * 16 + lr) * COLSTRIDE + quad * 16;
    const char* wb2 = lds_raw + (size_t)(2 * 16 + lr) * COLSTRIDE + quad * 16;
    const char* wb3 = lds_raw + (size_t)(3 * 16 + lr) * COLSTRIDE + quad * 16;

    for (int s = 0; s <= SEQ; ++s) {
        bool active = (layer == 0) ? (s < SEQ) : (s >= 1);
        if (active) {
            int t = (layer == 0) ? s : (s - 1);
            int parPrev = (s + 1) & 1;            // h0[s-1] parity
            const unsigned short *A1h_, *A1l_, *A2h_, *A2l_;
            if (layer == 0) {
                A1h_ = xh + ((size_t)s * BATCH + row0) * HID;   // x[s] (plain)
                A1l_ = xl + ((size_t)s * BATCH + row0) * HID;
                A2h_ = hh + (size_t)parPrev * HBSZ + (size_t)row0 * HID;  // h0[s-1]
                A2l_ = hl + (size_t)parPrev * HBSZ + (size_t)row0 * HID;
            } else {
                A1h_ = hh + (size_t)parPrev * HBSZ + (size_t)row0 * HID;  // h0[t]
                A1l_ = hl + (size_t)parPrev * HBSZ + (size_t)row0 * HID;
                A2h_ = hh + (size_t)(2 + (s & 1)) * HBSZ + (size_t)row0 * HID;  // h1[t-1]
                A2l_ = hl + (size_t)(2 + (s & 1)) * HBSZ + (size_t)row0 * HID;
            }

            floatx4 aA0 = {0.f, 0.f, 0.f, 0.f};
            floatx4 aB0 = {0.f, 0.f, 0.f, 0.f};
            floatx4 aA1 = {0.f, 0.f, 0.f, 0.f};
            floatx4 aB1 = {0.f, 0.f, 0.f, 0.f};

#define KBODY(A1LOAD) \
    _Pragma("unroll") \
    for (int kt = 0; kt < 16; ++kt) { \
        int ko = kt * 32; \
        short8 a1h = A1LOAD(A1h_ + aoff + ko); \
        short8 a1l = A1LOAD(A1l_ + aoff + ko); \
        short8 a2h = ald16(A2h_ + aoff + ko); \
        short8 a2l = ald16(A2l_ + aoff + ko); \
        short8 w1h = *(const short8*)(wb0 + kt * 64); \
        short8 w1l = *(const short8*)(wb1 + kt * 64); \
        short8 w2h = *(const short8*)(wb2 + kt * 64); \
        short8 w2l = *(const short8*)(wb3 + kt * 64); \
        floatx4& A  = (kt & 1) ? aA1 : aA0; \
        floatx4& Bq = (kt & 1) ? aB1 : aB0; \
        A  = __builtin_amdgcn_mfma_f32_16x16x32_bf16(a1h, w1h, A,  0, 0, 0); \
        Bq = __builtin_amdgcn_mfma_f32_16x16x32_bf16(a1l, w1h, Bq, 0, 0, 0); \
        A  = __builtin_amdgcn_mfma_f32_16x16x32_bf16(a1h, w1l, A,  0, 0, 0); \
        Bq = __builtin_amdgcn_mfma_f32_16x16x32_bf16(a2h, w2h, Bq, 0, 0, 0); \
        A  = __builtin_amdgcn_mfma_f32_16x16x32_bf16(a2l, w2h, A,  0, 0, 0); \
        Bq = __builtin_amdgcn_mfma_f32_16x16x32_bf16(a2h, w2l, Bq, 0, 0, 0); \
    }
            if (layer == 0) { KBODY(pld16) } else { KBODY(ald16) }
#undef KBODY

            int parOut = t & 1;
            unsigned short* hhout = hh + (size_t)(layer * 2 + parOut) * HBSZ;
            unsigned short* hlout = hl + (size_t)(layer * 2 + parOut) * HBSZ;
#define EPI(I, HOFF) { \
    float p = (aA0[I] + aB0[I]) + (aA1[I] + aB1[I]) + bv; \
    float e = __expf(2.0f * p); \
    float th = 1.0f - 2.0f / (e + 1.0f); \
    unsigned short thi_ = f2bf(th); \
    unsigned short tlo_ = f2bf(th - bf2f(thi_)); \
    GST_H((unsigned)thi_, hvoff, hhout, HOFF); \
    GST_H((unsigned)tlo_, hvoff, hlout, HOFF); \
    int row = row0 + quad * 4 + I; \
    if (layer == 1) { \
        out[((size_t)t * BATCH + row) * HID + col] = th; \
        if (t == SEQ - 1) \
            out[(size_t)SEQ * BATCH * HID + (size_t)(BATCH + row) * HID + col] = th; \
    } else if (t == SEQ - 1) { \
        out[(size_t)SEQ * BATCH * HID + (size_t)row * HID + col] = th; \
    } \
}
            EPI(0, 0) EPI(1, 1024) EPI(2, 2048) EPI(3, 3072)
#undef EPI
        }
        if (s < SEQ) {
            // release: drain sc1 h-stores to the coherence point
            asm volatile("s_waitcnt vmcnt(0)" ::: "memory");
            if (lane == 0) {
                __hip_atomic_fetch_add(cnt, 1u, __ATOMIC_RELAXED, __HIP_MEMORY_SCOPE_AGENT);
                unsigned target = 64u * (unsigned)(s + 1);
                while (__hip_atomic_load(cnt, __ATOMIC_RELAXED, __HIP_MEMORY_SCOPE_AGENT) < target)
                    __builtin_amdgcn_s_sleep(1);
            }
            asm volatile("" ::: "memory");
        }
    }
}

extern "C" void kernel_launch(void* const* d_in, const int* in_sizes, int n_in,
                              void* d_out, int out_size, void* d_ws, size_t ws_size,
                              hipStream_t stream) {
    const float* x    = (const float*)d_in[0];
    const float* h0in = (const float*)d_in[1];
    const float* Wx0  = (const float*)d_in[2];
    const float* bx0  = (const float*)d_in[3];
    const float* Wh0  = (const float*)d_in[4];
    const float* bh0  = (const float*)d_in[5];
    const float* Wx1  = (const float*)d_in[6];
    const float* bx1  = (const float*)d_in[7];
    const float* Wh1  = (const float*)d_in[8];
    const float* bh1  = (const float*)d_in[9];
    float* out = (float*)d_out;

    // workspace layout (all 256B aligned)
    char* w = (char*)d_ws;
    const size_t XN = (size_t)SEQ * BATCH * HID;          // 33,554,432
    unsigned short* xh  = (unsigned short*)(w);                       // 64 MB
    unsigned short* xl  = (unsigned short*)(w + 2 * XN);              // 64 MB
    unsigned short* Wth = (unsigned short*)(w + 4 * XN);              // 2 MB
    unsigned short* Wtl = (unsigned short*)(w + 4 * XN + 2097152);    // 2 MB
    float*          bsum= (float*)        (w + 4 * XN + 4194304);     // 4 KB
    unsigned short* hh  = (unsigned short*)(w + 4 * XN + 4198400);    // 256 KB
    unsigned short* hl  = (unsigned short*)(w + 4 * XN + 4460544);    // 256 KB
    unsigned int*   bar = (unsigned int*) (w + 4 * XN + 4722688);     // 1 KB
    // total ~132.5 MB

    split_x_kernel<<<4096, 256, 0, stream>>>(x, xh, xl, (int)(XN / 4));
    prep_w_kernel<<<2048, 256, 0, stream>>>(Wx0, bx0, Wh0, bh0, Wx1, bx1, Wh1, bh1,
                                            Wth, Wtl, bsum);
    init_h_kernel<<<256, 256, 0, stream>>>(h0in, hh, hl, bar);

    // persistent cooperative kernel: whole scan in one launch
    void* args[9] = {(void*)&xh, (void*)&xl, (void*)&Wth, (void*)&Wtl, (void*)&bsum,
                     (void*)&hh, (void*)&hl, (void*)&out, (void*)&bar};
    hipError_t err = hipLaunchCooperativeKernel((const void*)rnn_persist_kernel,
                                                dim3(256), dim3(64), args,
                                                (unsigned)(4 * 16 * COLSTRIDE), stream);
    if (err != hipSuccess) {
        // fallback: proven per-step path (no perf regression below baseline)
        for (int s = 0; s <= SEQ; ++s) {
            rnn_step_kernel<<<64, 256, 0, stream>>>(s, xh, xl, Wth, Wtl, bsum, hh, hl, out);
        }
    }
}